// Round 4
// baseline (532.297 us; speedup 1.0000x reference)
//
#include <hip/hip_runtime.h>
#include <hip/hip_bf16.h>

typedef __bf16 bf16x8 __attribute__((ext_vector_type(8)));
typedef float  f32x16 __attribute__((ext_vector_type(16)));

#define ALPHA_W 0.4f
#define NTOT 65536.0f

// output layout (float elements): [out 4*256*128*128][cov 8*32*32][eigen 32*32*32]
#define OUT_MAIN 16777216
#define OUT_COV  (OUT_MAIN)
#define OUT_EIG  (OUT_MAIN + 8192)

// ws float offsets
#define WS_CNT   0        // 16 ints (grid-barrier counters, zeroed by memset node)
#define WS_PSXY  16       // 512*1024 gram partials
#define WS_PSX   524304   // 512*32 channel-sum partials
#define WS_XA    540688   // 32*256 ct activations ping
#define WS_XB    548880   // 32*256 ct activations pong
#define WS_MUA   557072   // 4*256
#define WS_MUB   558096   // 4*256
#define WS_SMU   559120   // 4*256
#define WS_CT    560144   // 32*1024 s_CT
#define WS_M     592912   // 32*1024 (M = alpha*UDU + 0.6*I per (b,g))
#define WS_T     625680   // 32*32

struct Ptrs {
    const float* ctw[5]; const float* ctb[5];
    const float* muw[3]; const float* mub[3];
};

__device__ __forceinline__ float lrelu(float x) { return x >= 0.f ? x : 0.01f * x; }

__device__ __forceinline__ float dot256(const float* __restrict__ w, const float* __restrict__ x) {
    float a0 = 0.f, a1 = 0.f, a2 = 0.f, a3 = 0.f;
    #pragma unroll
    for (int i = 0; i < 256; i += 16) {
        float4 w0 = *(const float4*)(w + i);
        float4 w1 = *(const float4*)(w + i + 4);
        float4 w2 = *(const float4*)(w + i + 8);
        float4 w3 = *(const float4*)(w + i + 12);
        float4 x0 = *(const float4*)(x + i);
        float4 x1 = *(const float4*)(x + i + 4);
        float4 x2 = *(const float4*)(x + i + 8);
        float4 x3 = *(const float4*)(x + i + 12);
        a0 = fmaf(w0.x, x0.x, a0); a0 = fmaf(w0.y, x0.y, a0);
        a0 = fmaf(w0.z, x0.z, a0); a0 = fmaf(w0.w, x0.w, a0);
        a1 = fmaf(w1.x, x1.x, a1); a1 = fmaf(w1.y, x1.y, a1);
        a1 = fmaf(w1.z, x1.z, a1); a1 = fmaf(w1.w, x1.w, a1);
        a2 = fmaf(w2.x, x2.x, a2); a2 = fmaf(w2.y, x2.y, a2);
        a2 = fmaf(w2.z, x2.z, a2); a2 = fmaf(w2.w, x2.w, a2);
        a3 = fmaf(w3.x, x3.x, a3); a3 = fmaf(w3.y, x3.y, a3);
        a3 = fmaf(w3.z, x3.z, a3); a3 = fmaf(w3.w, x3.w, a3);
    }
    return (a0 + a1) + (a2 + a3);
}

__device__ __forceinline__ float dot128(const float* __restrict__ w, const float* __restrict__ x) {
    float a0 = 0.f, a1 = 0.f;
    #pragma unroll
    for (int i = 0; i < 128; i += 8) {
        float4 w0 = *(const float4*)(w + i);
        float4 w1 = *(const float4*)(w + i + 4);
        float4 x0 = *(const float4*)(x + i);
        float4 x1 = *(const float4*)(x + i + 4);
        a0 = fmaf(w0.x, x0.x, a0); a0 = fmaf(w0.y, x0.y, a0);
        a0 = fmaf(w0.z, x0.z, a0); a0 = fmaf(w0.w, x0.w, a0);
        a1 = fmaf(w1.x, x1.x, a1); a1 = fmaf(w1.y, x1.y, a1);
        a1 = fmaf(w1.z, x1.z, a1); a1 = fmaf(w1.w, x1.w, a1);
    }
    return a0 + a1;
}

// grid barrier among a fixed set of blocks (all co-resident: <=552 blocks, ample capacity)
__device__ __forceinline__ void gbar(int* c, int target) {
    __syncthreads();
    __threadfence();        // release: every thread's prior stores
    __syncthreads();
    if (threadIdx.x == 0) {
        atomicAdd(c, 1);
        while (__hip_atomic_load(c, __ATOMIC_ACQUIRE, __HIP_MEMORY_SCOPE_AGENT) < target)
            __builtin_amdgcn_s_sleep(2);
    }
    __syncthreads();
    __threadfence();        // acquire: invalidate stale cached lines
}

// blocks [0,512): per-group gram partials. blocks [512,552): MLP chain + finalize.
__global__ __launch_bounds__(256, 2) void gram_mlp(const float* __restrict__ cA,
                                                   const float* __restrict__ sB,
                                                   Ptrs p,
                                                   float* __restrict__ ws,
                                                   float* __restrict__ out) {
    int* cnt = (int*)(ws + WS_CNT);
    float* pSXY = ws + WS_PSXY;
    float* pSX  = ws + WS_PSX;
    float* XA   = ws + WS_XA;
    float* XB   = ws + WS_XB;
    float* MUA  = ws + WS_MUA;
    float* MUB  = ws + WS_MUB;
    float* SMU  = ws + WS_SMU;
    float* CT   = ws + WS_CT;
    float* M    = ws + WS_M;
    float* T    = ws + WS_T;
    int bid = blockIdx.x, tid = threadIdx.x;

    __shared__ float red[4][1024];
    __shared__ float sxr[4][64];
    __shared__ float sct[32 * 33], uu[32 * 33], ud[32 * 33];
    __shared__ float dinv[32], sxg[32], sh[256];

    if (bid < 512) {
        // ---------------- gram: g = bid>>6, 1024-wide n-slice ----------------
        int g = bid >> 6, slice = bid & 63;
        int w = tid >> 6, l = tid & 63;
        int col = l & 31, kq = l >> 5;
        int nbase = slice * 1024 + w * 256;     // one wave covers 256 n, stays inside one b
        int b = nbase >> 14, hw0 = nbase & 16383;
        const float* base = cA + (((size_t)(b * 256 + g * 32 + col)) << 14) + hw0 + kq * 8;
        f32x16 acc;
        #pragma unroll
        for (int r = 0; r < 16; r++) acc[r] = 0.f;
        float s0 = 0.f, s1 = 0.f;
        #pragma unroll 4
        for (int it = 0; it < 16; ++it) {
            float4 f0 = *(const float4*)(base + it * 16);
            float4 f1 = *(const float4*)(base + it * 16 + 4);
            s0 += (f0.x + f0.y) + (f0.z + f0.w);
            s1 += (f1.x + f1.y) + (f1.z + f1.w);
            bf16x8 v;
            v[0] = (__bf16)f0.x; v[1] = (__bf16)f0.y; v[2] = (__bf16)f0.z; v[3] = (__bf16)f0.w;
            v[4] = (__bf16)f1.x; v[5] = (__bf16)f1.y; v[6] = (__bf16)f1.z; v[7] = (__bf16)f1.w;
            acc = __builtin_amdgcn_mfma_f32_32x32x16_bf16(v, v, acc, 0, 0, 0);
        }
        sxr[w][l] = s0 + s1;
        #pragma unroll
        for (int r = 0; r < 16; r++) {
            int i = (r & 3) + 8 * (r >> 2) + 4 * kq;   // 32x32 C/D layout (symmetric matrix)
            red[w][i * 32 + col] = acc[r];
        }
        __syncthreads();
        for (int e = tid; e < 1024; e += 256)
            pSXY[(size_t)bid * 1024 + e] = red[0][e] + red[1][e] + red[2][e] + red[3][e];
        if (tid < 32) {
            float v = 0.f;
            #pragma unroll
            for (int ww = 0; ww < 4; ww++) v += sxr[ww][tid] + sxr[ww][tid + 32];
            pSX[bid * 32 + tid] = v;
        }
        // arrive at final barrier (no wait) and exit
        __syncthreads();
        __threadfence();
        __syncthreads();
        if (tid == 0) atomicAdd(&cnt[4], 1);
        return;
    }

    int m = bid - 512;   // [0,40)
    if (m < 32) {
        // ------------- ct chain: block m owns outs [m*8, m*8+8) for all 32 rows -------------
        int o = m * 8 + (tid >> 5);
        int r = tid & 31;                       // row = b*8+g
        const float* x0 = sB + (r >> 3) * 256 + (r & 7) * 32;
        {   // L0: 32 -> 256
            const float* wr = p.ctw[0] + o * 32;
            float a0 = 0.f, a1 = 0.f;
            #pragma unroll
            for (int i = 0; i < 32; i += 8) {
                float4 w0 = *(const float4*)(wr + i);
                float4 w1 = *(const float4*)(wr + i + 4);
                float4 v0 = *(const float4*)(x0 + i);
                float4 v1 = *(const float4*)(x0 + i + 4);
                a0 = fmaf(w0.x, v0.x, a0); a0 = fmaf(w0.y, v0.y, a0);
                a0 = fmaf(w0.z, v0.z, a0); a0 = fmaf(w0.w, v0.w, a0);
                a1 = fmaf(w1.x, v1.x, a1); a1 = fmaf(w1.y, v1.y, a1);
                a1 = fmaf(w1.z, v1.z, a1); a1 = fmaf(w1.w, v1.w, a1);
            }
            XA[r * 256 + o] = lrelu(a0 + a1 + p.ctb[0][o]);
        }
        gbar(&cnt[0], 40);
        XB[r * 256 + o] = lrelu(dot256(p.ctw[1] + (size_t)o * 256, XA + r * 256) + p.ctb[1][o]);
        gbar(&cnt[1], 40);
        XA[r * 256 + o] = lrelu(dot256(p.ctw[2] + (size_t)o * 256, XB + r * 256) + p.ctb[2][o]);
        gbar(&cnt[2], 40);
        XB[r * 256 + o] = lrelu(dot256(p.ctw[3] + (size_t)o * 256, XA + r * 256) + p.ctb[3][o]);
        gbar(&cnt[3], 40);
        // L4: 256 -> 1024, block owns outs [m*32, m*32+32)
        #pragma unroll
        for (int q = 0; q < 4; q++) {
            int oo = m * 32 + q * 8 + (tid >> 5);
            CT[r * 1024 + oo] = dot256(p.ctw[4] + (size_t)oo * 256, XB + r * 256) + p.ctb[4][oo];
        }
        gbar(&cnt[4], 552);   // also waits for gram partials

        // ------------- finalize row m: b = m>>3, g = m&7 -------------
        int b = m >> 3, g = m & 7;
        for (int e = tid; e < 1024; e += 256) sct[(e >> 5) * 33 + (e & 31)] = CT[m * 1024 + e];
        if (tid < 32) {
            float s = 0.f;
            for (int sl = 0; sl < 64; sl++) s += pSX[(g * 64 + sl) * 32 + tid];
            sxg[tid] = s * (1.0f / NTOT);
        }
        __syncthreads();
        if (tid < 32) {
            float s = 0.f;
            for (int i = 0; i < 32; i++) { float v = sct[i * 33 + tid]; s = fmaf(v, v, s); }
            dinv[tid] = 1.0f / sqrtf(s);
        }
        __syncthreads();
        float* eig = out + OUT_EIG + (size_t)(g * 4 + b) * 1024;
        for (int e = tid; e < 1024; e += 256) {
            int i = e >> 5, jj = e & 31;
            float u = sct[i * 33 + jj] * dinv[jj];
            uu[i * 33 + jj] = u;
            eig[e] = u;
        }
        __syncthreads();
        float* Mo = M + (size_t)m * 1024;
        for (int e = tid; e < 1024; e += 256) {
            int i = e >> 5, k = e & 31;
            float s = 0.f;
            for (int jv = 0; jv < 32; jv++) s = fmaf(sct[i * 33 + jv], uu[k * 33 + jv], s);
            ud[i * 33 + k] = s;
            Mo[e] = ALPHA_W * s + (i == k ? (1.0f - ALPHA_W) : 0.0f);
        }
        __syncthreads();
        if (tid < 32) {
            float s = 0.f;
            for (int k = 0; k < 32; k++) s = fmaf(ud[tid * 33 + k], sxg[k], s);
            T[m * 32 + tid] = ALPHA_W * (SMU[b * 256 + (m & 7) * 32 + tid] - s);
        }
    } else {
        // ------------- mu chain: block mm owns outs [mm*32, mm*32+32), rows 0..3, K split 2 ----
        int mm = m - 32;
        int h = tid >> 7, d = tid & 127;
        int o = mm * 32 + (d >> 2), r4 = d & 3;
        float v = dot128(p.muw[0] + (size_t)o * 256 + h * 128, sB + r4 * 256 + h * 128);
        sh[tid] = v; __syncthreads();
        if (h == 0) MUA[r4 * 256 + o] = lrelu(sh[d] + sh[d + 128] + p.mub[0][o]);
        gbar(&cnt[0], 40);
        v = dot128(p.muw[1] + (size_t)o * 256 + h * 128, MUA + r4 * 256 + h * 128);
        sh[tid] = v; __syncthreads();
        if (h == 0) MUB[r4 * 256 + o] = lrelu(sh[d] + sh[d + 128] + p.mub[1][o]);
        gbar(&cnt[1], 40);
        v = dot128(p.muw[2] + (size_t)o * 256 + h * 128, MUB + r4 * 256 + h * 128);
        sh[tid] = v; __syncthreads();
        if (h == 0) SMU[r4 * 256 + o] = sh[d] + sh[d + 128] + p.mub[2][o];
        gbar(&cnt[2], 40);
        gbar(&cnt[3], 40);
        gbar(&cnt[4], 552);
        // ------------- cov for group g = mm -------------
        int g = mm;
        if (tid < 32) {
            float s = 0.f;
            for (int sl = 0; sl < 64; sl++) s += pSX[(g * 64 + sl) * 32 + tid];
            sxg[tid] = s * (1.0f / NTOT);
        }
        __syncthreads();
        float* cov = out + OUT_COV + (size_t)g * 1024;
        for (int e = tid; e < 1024; e += 256) {
            float s = 0.f;
            for (int sl = 0; sl < 64; sl++) s += pSXY[(size_t)(g * 64 + sl) * 1024 + e];
            int i = e >> 5, jj = e & 31;
            float vv = (s - NTOT * sxg[i] * sxg[jj]) * (1.0f / (NTOT - 1.0f));
            if (i == jj) vv += 1e-5f;
            cov[e] = vv;
        }
    }
}

// out[b, g*32+i, n] = sum_k M[i,k]*cA[b, g*32+k, n] + t[i]
// grid 1024: bg = bid>>5, chunk = bid&31; 8 tiles of 64 cols, dbuf LDS, one sync/tile.
__global__ __launch_bounds__(256) void color_kernel(const float* __restrict__ cA,
                                                    const float* __restrict__ M,
                                                    const float* __restrict__ T,
                                                    float* __restrict__ out) {
    int bid = blockIdx.x;
    int bg = bid >> 5, chunk = bid & 31;
    int b = bg >> 3, g = bg & 7;
    int tid = threadIdx.x;
    int n = tid & 63, ih = tid >> 6;
    __shared__ float Ml[1024];
    __shared__ float tl[32];
    __shared__ float xs[2][2048];
    for (int e = tid; e < 1024; e += 256) Ml[e] = M[(size_t)bg * 1024 + e];
    if (tid < 32) tl[tid] = T[bg * 32 + tid];
    size_t cbase = (((size_t)(b * 256 + g * 32)) << 14) + chunk * 512;
    int srow = tid >> 3, scol = (tid & 7) * 8;
    size_t obase = (((size_t)(b * 256 + g * 32 + ih * 8)) << 14) + chunk * 512 + n;
    for (int tile = 0; tile < 8; ++tile) {
        const float* src = cA + cbase + (size_t)srow * 16384 + tile * 64 + scol;
        float4 u0 = *(const float4*)src;
        float4 u1 = *(const float4*)(src + 4);
        float* xd = &xs[tile & 1][srow * 64 + scol];
        *(float4*)xd = u0;
        *(float4*)(xd + 4) = u1;
        __syncthreads();
        const float* xb = xs[tile & 1];
        float acc[8];
        #pragma unroll
        for (int i = 0; i < 8; i++) acc[i] = tl[ih * 8 + i];
        for (int k = 0; k < 32; k++) {
            float xv = xb[k * 64 + n];
            #pragma unroll
            for (int i = 0; i < 8; i++) acc[i] = fmaf(Ml[(ih * 8 + i) * 32 + k], xv, acc[i]);
        }
        float* dst = out + obase + tile * 64;
        #pragma unroll
        for (int i = 0; i < 8; i++) dst[(size_t)i << 14] = acc[i];
    }
}

extern "C" void kernel_launch(void* const* d_in, const int* in_sizes, int n_in,
                              void* d_out, int out_size, void* d_ws, size_t ws_size,
                              hipStream_t stream) {
    (void)in_sizes; (void)n_in; (void)out_size; (void)ws_size;
    const float* cA = (const float*)d_in[0];
    const float* sB = (const float*)d_in[1];
    Ptrs p;
    p.ctw[0] = (const float*)d_in[3];  p.ctb[0] = (const float*)d_in[4];
    p.ctw[1] = (const float*)d_in[5];  p.ctb[1] = (const float*)d_in[6];
    p.ctw[2] = (const float*)d_in[7];  p.ctb[2] = (const float*)d_in[8];
    p.ctw[3] = (const float*)d_in[9];  p.ctb[3] = (const float*)d_in[10];
    p.ctw[4] = (const float*)d_in[11]; p.ctb[4] = (const float*)d_in[12];
    p.muw[0] = (const float*)d_in[13]; p.mub[0] = (const float*)d_in[14];
    p.muw[1] = (const float*)d_in[15]; p.mub[1] = (const float*)d_in[16];
    p.muw[2] = (const float*)d_in[17]; p.mub[2] = (const float*)d_in[18];
    float* W = (float*)d_ws;
    float* out = (float*)d_out;

    hipMemsetAsync(W + WS_CNT, 0, 16 * sizeof(int), stream);   // barrier counters
    gram_mlp<<<552, 256, 0, stream>>>(cA, sB, p, W, out);
    color_kernel<<<1024, 256, 0, stream>>>(cA, W + WS_M, W + WS_T, out);
}

// Round 5
// 276.236 us; speedup vs baseline: 1.9270x; 1.9270x over previous
//
#include <hip/hip_runtime.h>
#include <hip/hip_bf16.h>

typedef __bf16 bf16x8 __attribute__((ext_vector_type(8)));
typedef float  f32x16 __attribute__((ext_vector_type(16)));

#define ALPHA_W 0.4f
#define NTOT 65536.0f

// output layout (float elements): [out 4*256*128*128][cov 8*32*32][eigen 32*32*32]
#define OUT_MAIN 16777216
#define OUT_COV  (OUT_MAIN)
#define OUT_EIG  (OUT_MAIN + 8192)

// ws float offsets
#define WS_PSXY  0        // 512*1024 gram partials
#define WS_PSX   524288   // 512*32 channel-sum partials
#define WS_M     540672   // 32*1024 (M = alpha*UDU + 0.6*I per (b,g))
#define WS_T     573440   // 32*32

struct Ptrs {
    const float* ctw[5]; const float* ctb[5];
    const float* muw[3]; const float* mub[3];
};

__device__ __forceinline__ float lrelu(float x) { return x >= 0.f ? x : 0.01f * x; }

// fully-unrolled 256-dot: 64 float4 loads issued together -> ~1-2 latency rounds
__device__ __forceinline__ float dot256(const float* __restrict__ w, const float* __restrict__ x) {
    float a0 = 0.f, a1 = 0.f, a2 = 0.f, a3 = 0.f;
    #pragma unroll
    for (int i = 0; i < 256; i += 16) {
        float4 w0 = *(const float4*)(w + i);
        float4 w1 = *(const float4*)(w + i + 4);
        float4 w2 = *(const float4*)(w + i + 8);
        float4 w3 = *(const float4*)(w + i + 12);
        a0 = fmaf(w0.x, x[i + 0], a0);  a0 = fmaf(w0.y, x[i + 1], a0);
        a0 = fmaf(w0.z, x[i + 2], a0);  a0 = fmaf(w0.w, x[i + 3], a0);
        a1 = fmaf(w1.x, x[i + 4], a1);  a1 = fmaf(w1.y, x[i + 5], a1);
        a1 = fmaf(w1.z, x[i + 6], a1);  a1 = fmaf(w1.w, x[i + 7], a1);
        a2 = fmaf(w2.x, x[i + 8], a2);  a2 = fmaf(w2.y, x[i + 9], a2);
        a2 = fmaf(w2.z, x[i + 10], a2); a2 = fmaf(w2.w, x[i + 11], a2);
        a3 = fmaf(w3.x, x[i + 12], a3); a3 = fmaf(w3.y, x[i + 13], a3);
        a3 = fmaf(w3.z, x[i + 14], a3); a3 = fmaf(w3.w, x[i + 15], a3);
    }
    return (a0 + a1) + (a2 + a3);
}

// ---------- K1: per-group gram partials (MFMA, A-frag == B-frag) ----------
// grid 512: g = bid>>6, slice = bid&63 (1024-wide n-slice), 4 waves * 256 n.
__global__ __launch_bounds__(256) void gram_kernel(const float* __restrict__ cA,
                                                   float* __restrict__ pSXY,
                                                   float* __restrict__ pSX) {
    int bid = blockIdx.x;
    int g = bid >> 6, slice = bid & 63;
    int tid = threadIdx.x;
    int w = tid >> 6, l = tid & 63;
    int col = l & 31, kq = l >> 5;
    int nbase = slice * 1024 + w * 256;     // stays inside one b
    int b = nbase >> 14, hw0 = nbase & 16383;
    const float* base = cA + (((size_t)(b * 256 + g * 32 + col)) << 14) + hw0 + kq * 8;
    f32x16 acc;
    #pragma unroll
    for (int r = 0; r < 16; r++) acc[r] = 0.f;
    float s0 = 0.f, s1 = 0.f;
    #pragma unroll 4
    for (int it = 0; it < 16; ++it) {
        float4 f0 = *(const float4*)(base + it * 16);
        float4 f1 = *(const float4*)(base + it * 16 + 4);
        s0 += (f0.x + f0.y) + (f0.z + f0.w);
        s1 += (f1.x + f1.y) + (f1.z + f1.w);
        bf16x8 v;
        v[0] = (__bf16)f0.x; v[1] = (__bf16)f0.y; v[2] = (__bf16)f0.z; v[3] = (__bf16)f0.w;
        v[4] = (__bf16)f1.x; v[5] = (__bf16)f1.y; v[6] = (__bf16)f1.z; v[7] = (__bf16)f1.w;
        acc = __builtin_amdgcn_mfma_f32_32x32x16_bf16(v, v, acc, 0, 0, 0);
    }
    __shared__ float red[4][1024];
    __shared__ float sxr[4][64];
    sxr[w][l] = s0 + s1;
    #pragma unroll
    for (int r = 0; r < 16; r++) {
        int i = (r & 3) + 8 * (r >> 2) + 4 * kq;   // 32x32 C/D layout (symmetric matrix)
        red[w][i * 32 + col] = acc[r];
    }
    __syncthreads();
    for (int e = tid; e < 1024; e += 256)
        pSXY[(size_t)bid * 1024 + e] = red[0][e] + red[1][e] + red[2][e] + red[3][e];
    if (tid < 32) {
        float v = 0.f;
        #pragma unroll
        for (int ww = 0; ww < 4; ww++) v += sxr[ww][tid] + sxr[ww][tid + 32];
        pSX[bid * 32 + tid] = v;
    }
}

// ---------- K2: whole MLP chain + finalize, 40 blocks ----------
// blocks 0..31: (b,g) full ct chain + mu chain + D/U/eigen/UDU -> M, T
// blocks 32..39: g -> reduce gram partials -> cov
__global__ __launch_bounds__(256) void mlp_finalize(const float* __restrict__ sB,
                                                    Ptrs p,
                                                    const float* __restrict__ pSXY,
                                                    const float* __restrict__ pSX,
                                                    float* __restrict__ M,
                                                    float* __restrict__ T,
                                                    float* __restrict__ out) {
    int bid = blockIdx.x;
    int t = threadIdx.x;
    if (bid < 32) {
        int b = bid >> 3, g = bid & 7;
        __shared__ float ha[256], hb[256];
        __shared__ float sct[32 * 33], uu[32 * 33], ud[32 * 33];
        __shared__ float dinv[32], sxg[32];
        if (t < 32) {
            ha[t] = sB[b * 256 + g * 32 + t];
            float s = 0.f;
            #pragma unroll
            for (int sl = 0; sl < 64; sl++) s += pSX[(g * 64 + sl) * 32 + t];
            sxg[t] = s * (1.0f / NTOT);   // per-channel mean
        }
        __syncthreads();
        // ct L0: 32 -> 256
        {
            const float* wr = p.ctw[0] + t * 32;
            float a0 = 0.f, a1 = 0.f;
            #pragma unroll
            for (int i = 0; i < 32; i += 8) {
                float4 w0 = *(const float4*)(wr + i);
                float4 w1 = *(const float4*)(wr + i + 4);
                a0 = fmaf(w0.x, ha[i + 0], a0); a0 = fmaf(w0.y, ha[i + 1], a0);
                a0 = fmaf(w0.z, ha[i + 2], a0); a0 = fmaf(w0.w, ha[i + 3], a0);
                a1 = fmaf(w1.x, ha[i + 4], a1); a1 = fmaf(w1.y, ha[i + 5], a1);
                a1 = fmaf(w1.z, ha[i + 6], a1); a1 = fmaf(w1.w, ha[i + 7], a1);
            }
            hb[t] = lrelu(a0 + a1 + p.ctb[0][t]);
        }
        __syncthreads();
        ha[t] = lrelu(dot256(p.ctw[1] + (size_t)t * 256, hb) + p.ctb[1][t]);  __syncthreads();
        hb[t] = lrelu(dot256(p.ctw[2] + (size_t)t * 256, ha) + p.ctb[2][t]);  __syncthreads();
        ha[t] = lrelu(dot256(p.ctw[3] + (size_t)t * 256, hb) + p.ctb[3][t]);  __syncthreads();
        // ct L4: 256 -> 1024 (s_CT), 4 outputs/thread, no act
        #pragma unroll
        for (int q = 0; q < 4; q++) {
            int o = t + 256 * q;
            float v = dot256(p.ctw[4] + (size_t)o * 256, ha) + p.ctb[4][o];
            sct[(o >> 5) * 33 + (o & 31)] = v;
        }
        __syncthreads();
        // mu chain (reuse ha/hb): full 256-dim style row of batch b
        ha[t] = sB[b * 256 + t];                                              __syncthreads();
        hb[t] = lrelu(dot256(p.muw[0] + (size_t)t * 256, ha) + p.mub[0][t]);  __syncthreads();
        ha[t] = lrelu(dot256(p.muw[1] + (size_t)t * 256, hb) + p.mub[1][t]);  __syncthreads();
        hb[t] = dot256(p.muw[2] + (size_t)t * 256, ha) + p.mub[2][t];         // s_mu
        if (t < 32) {
            float s = 0.f;
            #pragma unroll
            for (int i = 0; i < 32; i++) { float v = sct[i * 33 + t]; s = fmaf(v, v, s); }
            dinv[t] = 1.0f / sqrtf(s);
        }
        __syncthreads();
        float* eig = out + OUT_EIG + (size_t)(g * 4 + b) * 1024;
        for (int e = t; e < 1024; e += 256) {
            int i = e >> 5, jj = e & 31;
            float u = sct[i * 33 + jj] * dinv[jj];
            uu[i * 33 + jj] = u;
            eig[e] = u;
        }
        __syncthreads();
        float* Mo = M + (size_t)bid * 1024;
        for (int e = t; e < 1024; e += 256) {
            int i = e >> 5, k = e & 31;
            float s = 0.f;
            #pragma unroll
            for (int jv = 0; jv < 32; jv++) s = fmaf(sct[i * 33 + jv], uu[k * 33 + jv], s);
            ud[i * 33 + k] = s;
            Mo[e] = ALPHA_W * s + (i == k ? (1.0f - ALPHA_W) : 0.0f);
        }
        __syncthreads();
        if (t < 32) {
            float s = 0.f;
            #pragma unroll
            for (int k = 0; k < 32; k++) s = fmaf(ud[t * 33 + k], sxg[k], s);
            T[bid * 32 + t] = ALPHA_W * (hb[g * 32 + t] - s);
        }
    } else {
        int g = bid - 32;
        __shared__ float sxg[32];
        if (t < 32) {
            float s = 0.f;
            #pragma unroll
            for (int sl = 0; sl < 64; sl++) s += pSX[(g * 64 + sl) * 32 + t];
            sxg[t] = s * (1.0f / NTOT);
        }
        __syncthreads();
        float* cov = out + OUT_COV + (size_t)g * 1024;
        for (int e = t; e < 1024; e += 256) {
            float s = 0.f;
            #pragma unroll
            for (int sl = 0; sl < 64; sl++) s += pSXY[(size_t)(g * 64 + sl) * 1024 + e];
            int i = e >> 5, jj = e & 31;
            float vv = (s - NTOT * sxg[i] * sxg[jj]) * (1.0f / (NTOT - 1.0f));
            if (i == jj) vv += 1e-5f;
            cov[e] = vv;
        }
    }
}

// ---------- K3: out[b, g*32+i, n] = sum_k M[i,k]*cA[b, g*32+k, n] + t[i] ----------
__global__ __launch_bounds__(256) void color_kernel(const float* __restrict__ cA,
                                                    const float* __restrict__ M,
                                                    const float* __restrict__ T,
                                                    float* __restrict__ out) {
    int bid = blockIdx.x;
    int bg = bid >> 5, chunk = bid & 31;
    int b = bg >> 3, g = bg & 7;
    int tid = threadIdx.x;
    int n = tid & 63, ih = tid >> 6;
    __shared__ float Ml[1024];
    __shared__ float tl[32];
    __shared__ float xs[2][2048];
    for (int e = tid; e < 1024; e += 256) Ml[e] = M[(size_t)bg * 1024 + e];
    if (tid < 32) tl[tid] = T[bg * 32 + tid];
    size_t cbase = (((size_t)(b * 256 + g * 32)) << 14) + chunk * 512;
    int srow = tid >> 3, scol = (tid & 7) * 8;
    size_t obase = (((size_t)(b * 256 + g * 32 + ih * 8)) << 14) + chunk * 512 + n;
    for (int tile = 0; tile < 8; ++tile) {
        const float* src = cA + cbase + (size_t)srow * 16384 + tile * 64 + scol;
        float4 u0 = *(const float4*)src;
        float4 u1 = *(const float4*)(src + 4);
        float* xd = &xs[tile & 1][srow * 64 + scol];
        *(float4*)xd = u0;
        *(float4*)(xd + 4) = u1;
        __syncthreads();
        const float* xb = xs[tile & 1];
        float acc[8];
        #pragma unroll
        for (int i = 0; i < 8; i++) acc[i] = tl[ih * 8 + i];
        #pragma unroll
        for (int k = 0; k < 32; k++) {
            float xv = xb[k * 64 + n];
            #pragma unroll
            for (int i = 0; i < 8; i++) acc[i] = fmaf(Ml[(ih * 8 + i) * 32 + k], xv, acc[i]);
        }
        float* dst = out + obase + tile * 64;
        #pragma unroll
        for (int i = 0; i < 8; i++) dst[(size_t)i << 14] = acc[i];
    }
}

extern "C" void kernel_launch(void* const* d_in, const int* in_sizes, int n_in,
                              void* d_out, int out_size, void* d_ws, size_t ws_size,
                              hipStream_t stream) {
    (void)in_sizes; (void)n_in; (void)out_size; (void)ws_size;
    const float* cA = (const float*)d_in[0];
    const float* sB = (const float*)d_in[1];
    Ptrs p;
    p.ctw[0] = (const float*)d_in[3];  p.ctb[0] = (const float*)d_in[4];
    p.ctw[1] = (const float*)d_in[5];  p.ctb[1] = (const float*)d_in[6];
    p.ctw[2] = (const float*)d_in[7];  p.ctb[2] = (const float*)d_in[8];
    p.ctw[3] = (const float*)d_in[9];  p.ctb[3] = (const float*)d_in[10];
    p.ctw[4] = (const float*)d_in[11]; p.ctb[4] = (const float*)d_in[12];
    p.muw[0] = (const float*)d_in[13]; p.mub[0] = (const float*)d_in[14];
    p.muw[1] = (const float*)d_in[15]; p.mub[1] = (const float*)d_in[16];
    p.muw[2] = (const float*)d_in[17]; p.mub[2] = (const float*)d_in[18];
    float* W = (float*)d_ws;
    float* out = (float*)d_out;

    gram_kernel<<<512, 256, 0, stream>>>(cA, W + WS_PSXY, W + WS_PSX);
    mlp_finalize<<<40, 256, 0, stream>>>(sB, p, W + WS_PSXY, W + WS_PSX,
                                         W + WS_M, W + WS_T, out);
    color_kernel<<<1024, 256, 0, stream>>>(cA, W + WS_M, W + WS_T, out);
}

// Round 7
// 226.095 us; speedup vs baseline: 2.3543x; 1.2218x over previous
//
#include <hip/hip_runtime.h>
#include <hip/hip_bf16.h>

typedef __bf16 bf16x8 __attribute__((ext_vector_type(8)));
typedef float  f32x16 __attribute__((ext_vector_type(16)));

#define ALPHA_W 0.4f
#define NTOT 65536.0f

// output layout (float elements): [out 4*256*128*128][cov 8*32*32][eigen 32*32*32]
#define OUT_MAIN 16777216
#define OUT_COV  (OUT_MAIN)
#define OUT_EIG  (OUT_MAIN + 8192)

// ws float offsets
#define WS_PSXY  0        // 512*1024 gram partials
#define WS_PSX   524288   // 512*32 channel-sum partials
#define WS_XA    540672   // 32*256 ct activations ping
#define WS_XB    548864   // 32*256 ct activations pong
#define WS_MUA   557056   // 4*256
#define WS_MUB   558080   // 4*256
#define WS_SMU   559104   // 4*256
#define WS_CT    560128   // 32*1024 s_CT
#define WS_M     592896   // 32*1024 (M = alpha*UDU + 0.6*I per (b,g))
#define WS_T     625664   // 32*32

struct LJ { const float* X; const float* W; const float* B; float* Y; int act; int out; };

__device__ __forceinline__ float lrelu(float x) { return x >= 0.f ? x : 0.01f * x; }

// fully-unrolled 256-dot, w from global, x from LDS (padded row, float4-aligned)
__device__ __forceinline__ float dotg256(const float* __restrict__ w, const float* __restrict__ x) {
    float a0 = 0.f, a1 = 0.f, a2 = 0.f, a3 = 0.f;
    #pragma unroll
    for (int i = 0; i < 256; i += 16) {
        float4 w0 = *(const float4*)(w + i);
        float4 w1 = *(const float4*)(w + i + 4);
        float4 w2 = *(const float4*)(w + i + 8);
        float4 w3 = *(const float4*)(w + i + 12);
        float4 x0 = *(const float4*)(x + i);
        float4 x1 = *(const float4*)(x + i + 4);
        float4 x2 = *(const float4*)(x + i + 8);
        float4 x3 = *(const float4*)(x + i + 12);
        a0 = fmaf(w0.x, x0.x, a0); a0 = fmaf(w0.y, x0.y, a0);
        a0 = fmaf(w0.z, x0.z, a0); a0 = fmaf(w0.w, x0.w, a0);
        a1 = fmaf(w1.x, x1.x, a1); a1 = fmaf(w1.y, x1.y, a1);
        a1 = fmaf(w1.z, x1.z, a1); a1 = fmaf(w1.w, x1.w, a1);
        a2 = fmaf(w2.x, x2.x, a2); a2 = fmaf(w2.y, x2.y, a2);
        a2 = fmaf(w2.z, x2.z, a2); a2 = fmaf(w2.w, x2.w, a2);
        a3 = fmaf(w3.x, x3.x, a3); a3 = fmaf(w3.y, x3.y, a3);
        a3 = fmaf(w3.z, x3.z, a3); a3 = fmaf(w3.w, x3.w, a3);
    }
    return (a0 + a1) + (a2 + a3);
}

// ---------- K1: per-group gram partials (MFMA, A-frag == B-frag) ----------
__global__ __launch_bounds__(256, 2) void gram_kernel(const float* __restrict__ cA,
                                                      float* __restrict__ pSXY,
                                                      float* __restrict__ pSX) {
    int bid = blockIdx.x;
    int g = bid >> 6, slice = bid & 63;
    int tid = threadIdx.x;
    int w = tid >> 6, l = tid & 63;
    int col = l & 31, kq = l >> 5;
    int nbase = slice * 1024 + w * 256;     // stays inside one b
    int b = nbase >> 14, hw0 = nbase & 16383;
    const float* base = cA + (((size_t)(b * 256 + g * 32 + col)) << 14) + hw0 + kq * 8;
    f32x16 acc;
    #pragma unroll
    for (int r = 0; r < 16; r++) acc[r] = 0.f;
    float s0 = 0.f, s1 = 0.f;
    #pragma unroll 8
    for (int it = 0; it < 16; ++it) {
        float4 f0 = *(const float4*)(base + it * 16);
        float4 f1 = *(const float4*)(base + it * 16 + 4);
        s0 += (f0.x + f0.y) + (f0.z + f0.w);
        s1 += (f1.x + f1.y) + (f1.z + f1.w);
        bf16x8 v;
        v[0] = (__bf16)f0.x; v[1] = (__bf16)f0.y; v[2] = (__bf16)f0.z; v[3] = (__bf16)f0.w;
        v[4] = (__bf16)f1.x; v[5] = (__bf16)f1.y; v[6] = (__bf16)f1.z; v[7] = (__bf16)f1.w;
        acc = __builtin_amdgcn_mfma_f32_32x32x16_bf16(v, v, acc, 0, 0, 0);
    }
    __shared__ float red[4][1024];
    __shared__ float sxr[4][64];
    sxr[w][l] = s0 + s1;
    #pragma unroll
    for (int r = 0; r < 16; r++) {
        int i = (r & 3) + 8 * (r >> 2) + 4 * kq;   // 32x32 C/D layout (symmetric matrix)
        red[w][i * 32 + col] = acc[r];
    }
    __syncthreads();
    for (int e = tid; e < 1024; e += 256)
        pSXY[(size_t)bid * 1024 + e] = red[0][e] + red[1][e] + red[2][e] + red[3][e];
    if (tid < 32) {
        float v = 0.f;
        #pragma unroll
        for (int ww = 0; ww < 4; ww++) v += sxr[ww][tid] + sxr[ww][tid + 32];
        pSX[bid * 32 + tid] = v;
    }
}

// ---------- K2: first MLP layer. blocks 0..31: ct L0 (in=32). blocks 32..35: mu L0 ----------
__global__ __launch_bounds__(256, 2) void lin_first(const float* __restrict__ sB,
                                                    const float* __restrict__ w0,
                                                    const float* __restrict__ b0,
                                                    float* __restrict__ XA,
                                                    const float* __restrict__ mw0,
                                                    const float* __restrict__ mb0,
                                                    float* __restrict__ MUA) {
    int bid = blockIdx.x, tid = threadIdx.x;
    if (bid < 32) {
        __shared__ float xls[32 * 36];      // row r = b*8+g: sB[r*32 + i] (identity r*32 = b*256+g*32)
        #pragma unroll
        for (int c = 0; c < 4; c++) {
            int idx = c * 256 + tid;        // all 1024 style elements
            xls[(idx >> 5) * 36 + (idx & 31)] = sB[idx];
        }
        __syncthreads();
        int o = bid * 8 + (tid & 7), r = tid >> 3;
        const float* wr = w0 + o * 32;
        const float* xr = xls + r * 36;
        float a0 = 0.f, a1 = 0.f;
        #pragma unroll
        for (int i = 0; i < 32; i += 8) {
            float4 u0 = *(const float4*)(wr + i);
            float4 u1 = *(const float4*)(wr + i + 4);
            float4 x0 = *(const float4*)(xr + i);
            float4 x1 = *(const float4*)(xr + i + 4);
            a0 = fmaf(u0.x, x0.x, a0); a0 = fmaf(u0.y, x0.y, a0);
            a0 = fmaf(u0.z, x0.z, a0); a0 = fmaf(u0.w, x0.w, a0);
            a1 = fmaf(u1.x, x1.x, a1); a1 = fmaf(u1.y, x1.y, a1);
            a1 = fmaf(u1.z, x1.z, a1); a1 = fmaf(u1.w, x1.w, a1);
        }
        XA[r * 256 + o] = lrelu(a0 + a1 + b0[o]);
    } else {
        __shared__ float xmu[4 * 260];
        {
            int idx = tid * 4;
            float4 v = *(const float4*)(sB + idx);
            *(float4*)(xmu + (idx >> 8) * 260 + (idx & 255)) = v;
        }
        __syncthreads();
        int o = (bid - 32) * 64 + (tid & 63), r = tid >> 6;
        float v = dotg256(mw0 + (size_t)o * 256, xmu + r * 260);
        MUA[r * 256 + o] = lrelu(v + mb0[o]);
    }
}

// ---------- K3: generic 256-in layer pair ----------
// blocks [0,nbA): ct-type (32 rows, 8 outs/block). blocks [nbA,...): mu-type (4 rows, 64 outs/block).
__global__ __launch_bounds__(256, 2) void lin256(LJ a, LJ b, int nbA) {
    int bid = blockIdx.x, tid = threadIdx.x;
    __shared__ float xls[32 * 260];
    if (bid < nbA) {
        #pragma unroll
        for (int c = 0; c < 8; c++) {
            int idx = c * 1024 + tid * 4;
            float4 v = *(const float4*)(a.X + idx);
            *(float4*)(xls + (idx >> 8) * 260 + (idx & 255)) = v;
        }
        __syncthreads();
        int o = bid * 8 + (tid & 7), r = tid >> 3;
        float v = dotg256(a.W + (size_t)o * 256, xls + r * 260) + a.B[o];
        a.Y[r * a.out + o] = a.act ? lrelu(v) : v;
    } else {
        {
            int idx = tid * 4;
            float4 v = *(const float4*)(b.X + idx);
            *(float4*)(xls + (idx >> 8) * 260 + (idx & 255)) = v;
        }
        __syncthreads();
        int o = (bid - nbA) * 64 + (tid & 63), r = tid >> 6;
        float v = dotg256(b.W + (size_t)o * 256, xls + r * 260) + b.B[o];
        b.Y[r * b.out + o] = b.act ? lrelu(v) : v;
    }
}

// ---------- K4: finalize. blocks 0..31: (b,g) U/eigen/UDU -> M,T. blocks 32..39: cov ----------
__global__ __launch_bounds__(256, 2) void finalize(const float* __restrict__ CT,
                                                   const float* __restrict__ SMU,
                                                   const float* __restrict__ pSXY,
                                                   const float* __restrict__ pSX,
                                                   float* __restrict__ M,
                                                   float* __restrict__ T,
                                                   float* __restrict__ out) {
    int bid = blockIdx.x, t = threadIdx.x;
    __shared__ float sxg[32];
    if (bid < 32) {
        int b = bid >> 3, g = bid & 7;
        __shared__ float sct[32 * 33], uu[32 * 33], ud[32 * 33], dinv[32];
        for (int e = t; e < 1024; e += 256) sct[(e >> 5) * 33 + (e & 31)] = CT[bid * 1024 + e];
        if (t < 32) {
            float s = 0.f;
            #pragma unroll
            for (int sl = 0; sl < 64; sl++) s += pSX[(g * 64 + sl) * 32 + t];
            sxg[t] = s * (1.0f / NTOT);
        }
        __syncthreads();
        if (t < 32) {
            float s = 0.f;
            #pragma unroll
            for (int i = 0; i < 32; i++) { float v = sct[i * 33 + t]; s = fmaf(v, v, s); }
            dinv[t] = 1.0f / sqrtf(s);
        }
        __syncthreads();
        float* eig = out + OUT_EIG + (size_t)(g * 4 + b) * 1024;
        for (int e = t; e < 1024; e += 256) {
            int i = e >> 5, jj = e & 31;
            float u = sct[i * 33 + jj] * dinv[jj];
            uu[i * 33 + jj] = u;
            eig[e] = u;
        }
        __syncthreads();
        float* Mo = M + (size_t)bid * 1024;
        for (int e = t; e < 1024; e += 256) {
            int i = e >> 5, k = e & 31;
            float s = 0.f;
            #pragma unroll
            for (int jv = 0; jv < 32; jv++) s = fmaf(sct[i * 33 + jv], uu[k * 33 + jv], s);
            ud[i * 33 + k] = s;
            Mo[e] = ALPHA_W * s + (i == k ? (1.0f - ALPHA_W) : 0.0f);
        }
        __syncthreads();
        if (t < 32) {
            float s = 0.f;
            #pragma unroll
            for (int k = 0; k < 32; k++) s = fmaf(ud[t * 33 + k], sxg[k], s);
            T[bid * 32 + t] = ALPHA_W * (SMU[bid * 32 + t] - s);
        }
    } else {
        int g = bid - 32;
        if (t < 32) {
            float s = 0.f;
            #pragma unroll
            for (int sl = 0; sl < 64; sl++) s += pSX[(g * 64 + sl) * 32 + t];
            sxg[t] = s * (1.0f / NTOT);
        }
        __syncthreads();
        float* cov = out + OUT_COV + (size_t)g * 1024;
        for (int e = t; e < 1024; e += 256) {
            float s = 0.f;
            #pragma unroll
            for (int sl = 0; sl < 64; sl++) s += pSXY[(size_t)(g * 64 + sl) * 1024 + e];
            int i = e >> 5, jj = e & 31;
            float vv = (s - NTOT * sxg[i] * sxg[jj]) * (1.0f / (NTOT - 1.0f));
            if (i == jj) vv += 1e-5f;
            cov[e] = vv;
        }
    }
}

// ---------- K5: out[b, g*32+i, n] = sum_k M[i,k]*cA[b, g*32+k, n] + t[i] ----------
__global__ __launch_bounds__(256) void color_kernel(const float* __restrict__ cA,
                                                    const float* __restrict__ M,
                                                    const float* __restrict__ T,
                                                    float* __restrict__ out) {
    int bid = blockIdx.x;
    int bg = bid >> 5, chunk = bid & 31;
    int b = bg >> 3, g = bg & 7;
    int tid = threadIdx.x;
    int n = tid & 63, ih = tid >> 6;
    __shared__ float Ml[1024];
    __shared__ float tl[32];
    __shared__ float xs[2][2048];
    for (int e = tid; e < 1024; e += 256) Ml[e] = M[(size_t)bg * 1024 + e];
    if (tid < 32) tl[tid] = T[bg * 32 + tid];
    size_t cbase = (((size_t)(b * 256 + g * 32)) << 14) + chunk * 512;
    int srow = tid >> 3, scol = (tid & 7) * 8;
    size_t obase = (((size_t)(b * 256 + g * 32 + ih * 8)) << 14) + chunk * 512 + n;
    for (int tile = 0; tile < 8; ++tile) {
        const float* src = cA + cbase + (size_t)srow * 16384 + tile * 64 + scol;
        float4 u0 = *(const float4*)src;
        float4 u1 = *(const float4*)(src + 4);
        float* xd = &xs[tile & 1][srow * 64 + scol];
        *(float4*)xd = u0;
        *(float4*)(xd + 4) = u1;
        __syncthreads();
        const float* xb = xs[tile & 1];
        float acc[8];
        #pragma unroll
        for (int i = 0; i < 8; i++) acc[i] = tl[ih * 8 + i];
        #pragma unroll
        for (int k = 0; k < 32; k++) {
            float xv = xb[k * 64 + n];
            #pragma unroll
            for (int i = 0; i < 8; i++) acc[i] = fmaf(Ml[(ih * 8 + i) * 32 + k], xv, acc[i]);
        }
        float* dst = out + obase + tile * 64;
        #pragma unroll
        for (int i = 0; i < 8; i++) dst[(size_t)i << 14] = acc[i];
    }
}

extern "C" void kernel_launch(void* const* d_in, const int* in_sizes, int n_in,
                              void* d_out, int out_size, void* d_ws, size_t ws_size,
                              hipStream_t stream) {
    (void)in_sizes; (void)n_in; (void)out_size; (void)ws_size;
    const float* cA = (const float*)d_in[0];
    const float* sB = (const float*)d_in[1];
    const float* ctw[5] = {(const float*)d_in[3], (const float*)d_in[5], (const float*)d_in[7],
                           (const float*)d_in[9], (const float*)d_in[11]};
    const float* ctb[5] = {(const float*)d_in[4], (const float*)d_in[6], (const float*)d_in[8],
                           (const float*)d_in[10], (const float*)d_in[12]};
    const float* muw[3] = {(const float*)d_in[13], (const float*)d_in[15], (const float*)d_in[17]};
    const float* mub[3] = {(const float*)d_in[14], (const float*)d_in[16], (const float*)d_in[18]};
    float* W = (float*)d_ws;
    float* out = (float*)d_out;

    gram_kernel<<<512, 256, 0, stream>>>(cA, W + WS_PSXY, W + WS_PSX);

    lin_first<<<36, 256, 0, stream>>>(sB, ctw[0], ctb[0], W + WS_XA, muw[0], mub[0], W + WS_MUA);
    LJ a, b;
    a = {W + WS_XA, ctw[1], ctb[1], W + WS_XB, 1, 256};
    b = {W + WS_MUA, muw[1], mub[1], W + WS_MUB, 1, 256};
    lin256<<<36, 256, 0, stream>>>(a, b, 32);
    a = {W + WS_XB, ctw[2], ctb[2], W + WS_XA, 1, 256};
    b = {W + WS_MUB, muw[2], mub[2], W + WS_SMU, 0, 256};
    lin256<<<36, 256, 0, stream>>>(a, b, 32);
    a = {W + WS_XA, ctw[3], ctb[3], W + WS_XB, 1, 256};
    lin256<<<32, 256, 0, stream>>>(a, a, 32);
    a = {W + WS_XB, ctw[4], ctb[4], W + WS_CT, 0, 1024};
    lin256<<<128, 256, 0, stream>>>(a, a, 128);

    finalize<<<40, 256, 0, stream>>>(W + WS_CT, W + WS_SMU, W + WS_PSXY, W + WS_PSX,
                                     W + WS_M, W + WS_T, out);
    color_kernel<<<1024, 256, 0, stream>>>(cA, W + WS_M, W + WS_T, out);
}